// Round 10
// baseline (434.082 us; speedup 1.0000x reference)
//
#include <hip/hip_runtime.h>
#include <hip/hip_bf16.h>

#define N_DST1 50000
#define N_DST2 10000
#define FEAT   256

typedef unsigned int u32;
typedef unsigned char u8;
typedef __attribute__((ext_vector_type(4))) float f32x4;
typedef __attribute__((ext_vector_type(8))) short bf16x8;

__device__ __forceinline__ ushort f2bf(float f) {
    u32 u = __float_as_uint(f);
    u32 r = (u + 0x7FFFu + ((u >> 16) & 1u)) >> 16;
    return (ushort)r;
}
__device__ __forceinline__ float bf2f(ushort u) {
    return __uint_as_float(((u32)u) << 16);
}
__device__ __forceinline__ u8 f2fp8(float f) {
    u32 pk = __builtin_amdgcn_cvt_pk_fp8_f32(f, f, 0, false);
    return (u8)(pk & 0xFF);
}

__device__ __forceinline__ void gload_lds16(const void* g, void* l) {
    __builtin_amdgcn_global_load_lds(
        (const __attribute__((address_space(1))) u32*)g,
        (__attribute__((address_space(3))) u32*)l, 16, 0, 0);
}

// ---------------- fused prep: x -> fp8(all rows) + bf16(head rows) + degree count ----------------
__global__ __launch_bounds__(256) void prep_kernel(
    const float* __restrict__ x, ushort* __restrict__ xb, u32* __restrict__ xq,
    int n8, int n8h,
    const int* __restrict__ dst1, int E1, int* __restrict__ deg1,
    const int* __restrict__ dst2, int E2, int* __restrict__ deg2)
{
    int gid = blockIdx.x * blockDim.x + threadIdx.x;
    if (gid < n8) {
        const f32x4* p = (const f32x4*)x + (size_t)gid * 2;
        f32x4 a = __builtin_nontemporal_load(p);
        f32x4 b = __builtin_nontemporal_load(p + 1);
        if (xq) {
            u32 w0 = 0, w1 = 0;
            w0 = __builtin_amdgcn_cvt_pk_fp8_f32(a.x, a.y, w0, false);
            w0 = __builtin_amdgcn_cvt_pk_fp8_f32(a.z, a.w, w0, true);
            w1 = __builtin_amdgcn_cvt_pk_fp8_f32(b.x, b.y, w1, false);
            w1 = __builtin_amdgcn_cvt_pk_fp8_f32(b.z, b.w, w1, true);
            uint2 wv; wv.x = w0; wv.y = w1;
            *((uint2*)xq + gid) = wv;
        }
        if (gid < n8h) {
            ushort4 lo = make_ushort4(f2bf(a.x), f2bf(a.y), f2bf(a.z), f2bf(a.w));
            ushort4 hi = make_ushort4(f2bf(b.x), f2bf(b.y), f2bf(b.z), f2bf(b.w));
            ushort4* q = (ushort4*)xb + (size_t)gid * 2;
            q[0] = lo; q[1] = hi;
        }
        return;
    }
    int e = gid - n8;
    int e14 = E1 >> 2, e24 = E2 >> 2;
    if (e < e14) {
        int4 d4 = reinterpret_cast<const int4*>(dst1)[e];
        atomicAdd(&deg1[d4.x], 1); atomicAdd(&deg1[d4.y], 1);
        atomicAdd(&deg1[d4.z], 1); atomicAdd(&deg1[d4.w], 1);
        return;
    }
    e -= e14;
    if (e < e24) {
        int4 d4 = reinterpret_cast<const int4*>(dst2)[e];
        atomicAdd(&deg2[d4.x], 1); atomicAdd(&deg2[d4.y], 1);
        atomicAdd(&deg2[d4.z], 1); atomicAdd(&deg2[d4.w], 1);
        return;
    }
    e -= e24;
    int r1 = E1 & 3;
    if (e < r1) { atomicAdd(&deg1[dst1[E1 - r1 + e]], 1); return; }
    e -= r1;
    int r2 = E2 & 3;
    if (e < r2) { atomicAdd(&deg2[dst2[E2 - r2 + e]], 1); return; }
}

// ---------------- fused: dual exclusive scan (blocks 0,1) + W transposes (blocks 2..513) ----------------
__global__ __launch_bounds__(1024) void scan_wt_kernel(
    const int* __restrict__ degA, int nA, int* __restrict__ offA, int* __restrict__ posA,
    const int* __restrict__ degB, int nB, int* __restrict__ offB, int* __restrict__ posB,
    const float* __restrict__ W1, ushort* __restrict__ W1T,
    const float* __restrict__ W2, ushort* __restrict__ W2T)
{
    if (blockIdx.x >= 2) {
        int k = blockIdx.x - 2;           // 512 k-rows
        int t = threadIdx.x;
        if (t < 256) W1T[(size_t)t * 512 + k] = f2bf(W1[(size_t)k * 256 + t]);
        else if (t < 320) {
            int n = t - 256;
            W2T[(size_t)n * 512 + k] = f2bf(W2[(size_t)k * 64 + n]);
        }
        return;
    }
    const int* deg = (blockIdx.x == 0) ? degA : degB;
    int*       off = (blockIdx.x == 0) ? offA : offB;
    int*       pos = (blockIdx.x == 0) ? posA : posB;
    int n = (blockIdx.x == 0) ? nA : nB;
    int n4 = n >> 2;

    __shared__ int wsum[16];
    __shared__ int carry_s;
    int t = threadIdx.x;
    int lane = t & 63, wid = t >> 6;
    if (t == 0) carry_s = 0;
    __syncthreads();
    for (int base = 0; base < n4; base += 1024) {
        int i = base + t;
        int4 v = make_int4(0, 0, 0, 0);
        if (i < n4) v = reinterpret_cast<const int4*>(deg)[i];
        int tot = v.x + v.y + v.z + v.w;
        int s = tot;
        #pragma unroll
        for (int d = 1; d < 64; d <<= 1) {
            int u = __shfl_up(s, d, 64);
            if (lane >= d) s += u;
        }
        if (lane == 63) wsum[wid] = s;
        __syncthreads();
        if (wid == 0 && lane < 16) {
            int ws = wsum[lane];
            #pragma unroll
            for (int d = 1; d < 16; d <<= 1) {
                int u = __shfl_up(ws, d, 64);
                if (lane >= d) ws += u;
            }
            wsum[lane] = ws;
        }
        __syncthreads();
        int waveoff = (wid == 0) ? 0 : wsum[wid - 1];
        int carry = carry_s;
        int base0 = carry + waveoff + s - tot;
        if (i < n4) {
            int4 e;
            e.x = base0;
            e.y = base0 + v.x;
            e.z = base0 + v.x + v.y;
            e.w = base0 + v.x + v.y + v.z;
            reinterpret_cast<int4*>(off)[i] = e;
            reinterpret_cast<int4*>(pos)[i] = e;
        }
        __syncthreads();
        if (t == 0) carry_s = carry + wsum[15];
        __syncthreads();
    }
    if (t == 0) off[n] = carry_s;
}

// ---------------- merged scatter (both graphs), 4 edges/thread ----------------
__global__ void scatter_csr2_kernel(const int* __restrict__ src1, const int* __restrict__ dst1,
                                    int E1, int* __restrict__ pos1, int* __restrict__ csr1,
                                    const int* __restrict__ src2, const int* __restrict__ dst2,
                                    int E2, int* __restrict__ pos2, int* __restrict__ csr2) {
    int e = blockIdx.x * blockDim.x + threadIdx.x;
    int e14 = E1 >> 2, e24 = E2 >> 2;
    if (e < e14) {
        int4 s4 = reinterpret_cast<const int4*>(src1)[e];
        int4 d4 = reinterpret_cast<const int4*>(dst1)[e];
        csr1[atomicAdd(&pos1[d4.x], 1)] = s4.x;
        csr1[atomicAdd(&pos1[d4.y], 1)] = s4.y;
        csr1[atomicAdd(&pos1[d4.z], 1)] = s4.z;
        csr1[atomicAdd(&pos1[d4.w], 1)] = s4.w;
        return;
    }
    e -= e14;
    if (e < e24) {
        int4 s4 = reinterpret_cast<const int4*>(src2)[e];
        int4 d4 = reinterpret_cast<const int4*>(dst2)[e];
        csr2[atomicAdd(&pos2[d4.x], 1)] = s4.x;
        csr2[atomicAdd(&pos2[d4.y], 1)] = s4.y;
        csr2[atomicAdd(&pos2[d4.z], 1)] = s4.z;
        csr2[atomicAdd(&pos2[d4.w], 1)] = s4.w;
        return;
    }
    e -= e24;
    int r1 = E1 & 3;
    if (e < r1) {
        int i = E1 - r1 + e;
        csr1[atomicAdd(&pos1[dst1[i]], 1)] = src1[i];
        return;
    }
    e -= r1;
    int r2 = E2 & 3;
    if (e < r2) {
        int i = E2 - r2 + e;
        csr2[atomicAdd(&pos2[dst2[i]], 1)] = src2[i];
        return;
    }
}

// ---------------- seg1: XCD-chunked fp8 segment mean ----------------
// chunk c = blockIdx&7 -> 32 features [32c,32c+32); thread-per-dst; working set/chunk = 6.4MB.
__global__ __launch_bounds__(256) void seg_mean_fp8_chunked_kernel(
    const u8* __restrict__ Xq, const int* __restrict__ off,
    const int* __restrict__ csr, ushort* __restrict__ out, int ndst)
{
    int c = blockIdx.x & 7;
    int d = (blockIdx.x >> 3) * 256 + threadIdx.x;
    if (d >= ndst) return;
    int beg = off[d], end = off[d + 1];
    float acc[32];
    #pragma unroll
    for (int q = 0; q < 32; ++q) acc[q] = 0.f;
    const u8* base = Xq + (size_t)c * 32;
    int j = beg;
    for (; j + 2 <= end; j += 2) {
        int r0 = csr[j], r1 = csr[j + 1];
        uint4 a0 = *reinterpret_cast<const uint4*>(base + (size_t)r0 * 256);
        uint4 a1 = *reinterpret_cast<const uint4*>(base + (size_t)r0 * 256 + 16);
        uint4 b0 = *reinterpret_cast<const uint4*>(base + (size_t)r1 * 256);
        uint4 b1 = *reinterpret_cast<const uint4*>(base + (size_t)r1 * 256 + 16);
        u32 wa[8] = {a0.x, a0.y, a0.z, a0.w, a1.x, a1.y, a1.z, a1.w};
        u32 wb[8] = {b0.x, b0.y, b0.z, b0.w, b1.x, b1.y, b1.z, b1.w};
        #pragma unroll
        for (int q = 0; q < 8; ++q) {
            auto alo = __builtin_amdgcn_cvt_pk_f32_fp8(wa[q], false);
            auto ahi = __builtin_amdgcn_cvt_pk_f32_fp8(wa[q], true);
            auto blo = __builtin_amdgcn_cvt_pk_f32_fp8(wb[q], false);
            auto bhi = __builtin_amdgcn_cvt_pk_f32_fp8(wb[q], true);
            acc[q * 4 + 0] += alo[0] + blo[0];
            acc[q * 4 + 1] += alo[1] + blo[1];
            acc[q * 4 + 2] += ahi[0] + bhi[0];
            acc[q * 4 + 3] += ahi[1] + bhi[1];
        }
    }
    if (j < end) {
        int r0 = csr[j];
        uint4 a0 = *reinterpret_cast<const uint4*>(base + (size_t)r0 * 256);
        uint4 a1 = *reinterpret_cast<const uint4*>(base + (size_t)r0 * 256 + 16);
        u32 wa[8] = {a0.x, a0.y, a0.z, a0.w, a1.x, a1.y, a1.z, a1.w};
        #pragma unroll
        for (int q = 0; q < 8; ++q) {
            auto alo = __builtin_amdgcn_cvt_pk_f32_fp8(wa[q], false);
            auto ahi = __builtin_amdgcn_cvt_pk_f32_fp8(wa[q], true);
            acc[q * 4 + 0] += alo[0];
            acc[q * 4 + 1] += alo[1];
            acc[q * 4 + 2] += ahi[0];
            acc[q * 4 + 3] += ahi[1];
        }
    }
    float sc = 1.0f / (float)max(end - beg, 1);
    ushort* ob = out + (size_t)d * FEAT + c * 32;
    #pragma unroll
    for (int g = 0; g < 4; ++g) {
        bf16x8 ov;
        #pragma unroll
        for (int q = 0; q < 8; ++q) ov[q] = (short)f2bf(acc[g * 8 + q] * sc);
        *reinterpret_cast<bf16x8*>(ob + g * 8) = ov;
    }
}

// ---------------- seg2: fp8 gather, wave-per-dst (working set L2-resident) ----------------
__global__ __launch_bounds__(512) void seg_mean_fp8_kernel(
    const u32* __restrict__ Xq, const int* __restrict__ off,
    const int* __restrict__ csr, ushort* __restrict__ out, int ndst)
{
    int wid = threadIdx.x >> 6;
    int d = blockIdx.x * 8 + wid;
    if (d >= ndst) return;
    int l = threadIdx.x & 63;
    int sub = l >> 4;
    int lg = l & 15;
    int beg = off[d], end = off[d + 1];
    float acc[16];
    #pragma unroll
    for (int q = 0; q < 16; ++q) acc[q] = 0.f;
    for (int j = beg; j < end; j += 8) {
        int i0 = j + sub, i1 = j + 4 + sub;
        int r0 = csr[min(i0, end - 1)];
        int r1 = csr[min(i1, end - 1)];
        uint4 v0 = *reinterpret_cast<const uint4*>(Xq + (size_t)r0 * 64 + lg * 4);
        uint4 v1 = *reinterpret_cast<const uint4*>(Xq + (size_t)r1 * 64 + lg * 4);
        float m0 = (i0 < end) ? 1.f : 0.f;
        float m1 = (i1 < end) ? 1.f : 0.f;
        u32 w0[4] = {v0.x, v0.y, v0.z, v0.w};
        u32 w1[4] = {v1.x, v1.y, v1.z, v1.w};
        #pragma unroll
        for (int w = 0; w < 4; ++w) {
            auto a01 = __builtin_amdgcn_cvt_pk_f32_fp8(w0[w], false);
            auto a23 = __builtin_amdgcn_cvt_pk_f32_fp8(w0[w], true);
            auto b01 = __builtin_amdgcn_cvt_pk_f32_fp8(w1[w], false);
            auto b23 = __builtin_amdgcn_cvt_pk_f32_fp8(w1[w], true);
            acc[w * 4 + 0] += m0 * a01[0] + m1 * b01[0];
            acc[w * 4 + 1] += m0 * a01[1] + m1 * b01[1];
            acc[w * 4 + 2] += m0 * a23[0] + m1 * b23[0];
            acc[w * 4 + 3] += m0 * a23[1] + m1 * b23[1];
        }
    }
    #pragma unroll
    for (int q = 0; q < 16; ++q) {
        acc[q] += __shfl_xor(acc[q], 16);
        acc[q] += __shfl_xor(acc[q], 32);
    }
    if (l < 16) {
        float sc = 1.0f / (float)max(end - beg, 1);
        bf16x8 o0, o1;
        #pragma unroll
        for (int q = 0; q < 8; ++q) {
            o0[q] = (short)f2bf(acc[q] * sc);
            o1[q] = (short)f2bf(acc[8 + q] * sc);
        }
        ushort* base = out + (size_t)d * FEAT + lg * 16;
        *reinterpret_cast<bf16x8*>(base) = o0;
        *reinterpret_cast<bf16x8*>(base + 8) = o1;
    }
}

// ---------------- segment mean (bf16 gather) — fallback ----------------
__global__ __launch_bounds__(512) void seg_mean_bf16_kernel(
    const ushort* __restrict__ X, const int* __restrict__ off,
    const int* __restrict__ csr, ushort* __restrict__ out, int ndst)
{
    int wid = threadIdx.x >> 6;
    int d = blockIdx.x * 8 + wid;
    if (d >= ndst) return;
    int l = threadIdx.x & 63;
    int half = l >> 5;
    int f8 = (l & 31) * 8;
    int beg = off[d], end = off[d + 1];
    float acc[8] = {0.f, 0.f, 0.f, 0.f, 0.f, 0.f, 0.f, 0.f};
    for (int j = beg; j < end; j += 8) {
        #pragma unroll
        for (int p = 0; p < 4; ++p) {
            int idx = j + p * 2 + half;
            int r = csr[min(idx, end - 1)];
            bf16x8 v = *reinterpret_cast<const bf16x8*>(&X[(size_t)r * FEAT + f8]);
            float m = (idx < end) ? 1.f : 0.f;
            #pragma unroll
            for (int q = 0; q < 8; ++q) acc[q] += m * bf2f((ushort)v[q]);
        }
    }
    #pragma unroll
    for (int q = 0; q < 8; ++q) acc[q] += __shfl_xor(acc[q], 32);
    if (l < 32) {
        float sc = 1.0f / (float)max(end - beg, 1);
        bf16x8 ov;
        #pragma unroll
        for (int q = 0; q < 8; ++q) ov[q] = (short)f2bf(acc[q] * sc);
        *reinterpret_cast<bf16x8*>(&out[(size_t)d * FEAT + f8]) = ov;
    }
}

// ---------------- f32-gather fallback (small ws) ----------------
__global__ void seg_mean_f32_kernel(const float* __restrict__ X, const int* __restrict__ off,
                                    const int* __restrict__ csr, ushort* __restrict__ out) {
    int d = blockIdx.x;
    int t = threadIdx.x;
    int beg = off[d], end = off[d + 1];
    float a0 = 0.f, a1 = 0.f, a2 = 0.f, a3 = 0.f;
    for (int j = beg; j < end; ++j) {
        int s = csr[j];
        float4 v = *reinterpret_cast<const float4*>(&X[(size_t)s * FEAT + t * 4]);
        a0 += v.x; a1 += v.y; a2 += v.z; a3 += v.w;
    }
    float sc = 1.0f / (float)max(end - beg, 1);
    ushort4 o = make_ushort4(f2bf(a0 * sc), f2bf(a1 * sc), f2bf(a2 * sc), f2bf(a3 * sc));
    *reinterpret_cast<ushort4*>(&out[(size_t)d * FEAT + t * 4]) = o;
}

// ---------------- bf16 MFMA GEMM: C = concat(A0,A1) @ BT^T + bias (+ optional fp8 copy) ----------------
template<int BM, int BN, int WGM, int WGN, bool RELU, bool OBF16, bool WQ8>
__global__ __launch_bounds__(WGM * WGN * 64)
void gemm_mfma_kernel(const ushort* __restrict__ A0, const ushort* __restrict__ A1,
                      const ushort* __restrict__ BT, const float* __restrict__ bias,
                      ushort* __restrict__ Cb, float* __restrict__ Cf, u8* __restrict__ Cq,
                      int M, int Nfull) {
    constexpr int NWAVE = WGM * WGN;
    constexpr int WM = BM / WGM;
    constexpr int WN = BN / WGN;
    constexpr int MF = WM / 16;
    constexpr int NF = WN / 16;
    constexpr int ACH = BM / 16;
    constexpr int BCH = BN / 16;

    __shared__ ushort Al[2][BM][32];
    __shared__ ushort Bl[2][BN][32];

    const int t = threadIdx.x;
    const int lane = t & 63;
    const int wid = t >> 6;
    const int wm = wid / WGN, wn = wid % WGN;
    const int lr = lane & 15, grp = lane >> 4;
    const int rowBase = blockIdx.y * BM;
    const int colBase = blockIdx.x * BN;

    f32x4 acc[MF][NF];
    #pragma unroll
    for (int m = 0; m < MF; ++m)
        #pragma unroll
        for (int n = 0; n < NF; ++n)
            acc[m][n] = (f32x4){0.f, 0.f, 0.f, 0.f};

    auto stage = [&](int buf, int kt) {
        const ushort* Asrc = (kt < 8) ? A0 : A1;
        const int kcol = (kt * 32) & 255;
        #pragma unroll
        for (int ch = wid; ch < ACH; ch += NWAVE) {
            int r = ch * 16 + (lane >> 2);
            int rg = min(rowBase + r, M - 1);
            int c = lane & 3;
            int ksw = (c ^ (r & 3)) * 8;
            gload_lds16(&Asrc[(size_t)rg * 256 + kcol + ksw], &Al[buf][ch * 16][0]);
        }
        #pragma unroll
        for (int ch = wid; ch < BCH; ch += NWAVE) {
            int r = ch * 16 + (lane >> 2);
            int c = lane & 3;
            int ksw = (c ^ (r & 3)) * 8;
            gload_lds16(&BT[(size_t)(colBase + r) * 512 + kt * 32 + ksw], &Bl[buf][ch * 16][0]);
        }
    };

    stage(0, 0);
    __syncthreads();

    int buf = 0;
    for (int kt = 0; kt < 16; ++kt) {
        if (kt + 1 < 16) stage(buf ^ 1, kt + 1);
        bf16x8 af[MF], bfr[NF];
        #pragma unroll
        for (int m = 0; m < MF; ++m) {
            int r = wm * WM + m * 16 + lr;
            af[m] = *reinterpret_cast<const bf16x8*>(
                (const char*)&Al[buf][0][0] + r * 64 + ((grp ^ (r & 3)) << 4));
        }
        #pragma unroll
        for (int n = 0; n < NF; ++n) {
            int r = wn * WN + n * 16 + lr;
            bfr[n] = *reinterpret_cast<const bf16x8*>(
                (const char*)&Bl[buf][0][0] + r * 64 + ((grp ^ (r & 3)) << 4));
        }
        #pragma unroll
        for (int m = 0; m < MF; ++m)
            #pragma unroll
            for (int n = 0; n < NF; ++n)
                acc[m][n] = __builtin_amdgcn_mfma_f32_16x16x32_bf16(af[m], bfr[n], acc[m][n], 0, 0, 0);
        __syncthreads();
        buf ^= 1;
    }

    #pragma unroll
    for (int m = 0; m < MF; ++m) {
        #pragma unroll
        for (int q = 0; q < 4; ++q) {
            int rowg = rowBase + wm * WM + m * 16 + grp * 4 + q;
            if (rowg >= M) continue;
            #pragma unroll
            for (int n = 0; n < NF; ++n) {
                int colg = colBase + wn * WN + n * 16 + lr;
                float v = acc[m][n][q] + bias[colg];
                if (RELU) v = fmaxf(v, 0.f);
                if (OBF16) Cb[(size_t)rowg * Nfull + colg] = f2bf(v);
                else       Cf[(size_t)rowg * Nfull + colg] = v;
                if (WQ8)   Cq[(size_t)rowg * Nfull + colg] = f2fp8(v);
            }
        }
    }
}

extern "C" void kernel_launch(void* const* d_in, const int* in_sizes, int n_in,
                              void* d_out, int out_size, void* d_ws, size_t ws_size,
                              hipStream_t stream) {
    const float* x  = (const float*)d_in[0];
    const float* W1 = (const float*)d_in[1];
    const float* b1 = (const float*)d_in[2];
    const float* W2 = (const float*)d_in[3];
    const float* b2 = (const float*)d_in[4];
    const int* src1 = (const int*)d_in[5];
    const int* dst1 = (const int*)d_in[6];
    const int* src2 = (const int*)d_in[7];
    const int* dst2 = (const int*)d_in[8];
    const int E1 = in_sizes[5];
    const int E2 = in_sizes[7];
    const int N_SRC1 = in_sizes[0] / FEAT;   // 200000
    float* out = (float*)d_out;

    char* ws = (char*)d_ws;
    size_t o = 0;
    auto carve = [&](size_t bytes) { char* p = ws + o; o = (o + bytes + 255) & ~(size_t)255; return p; };
    int*    degs = (int*)   carve((size_t)(N_DST1 + N_DST2) * 4);
    int*    deg1 = degs;
    int*    deg2 = degs + N_DST1;
    int*    off1 = (int*)   carve((size_t)(N_DST1 + 1) * 4);
    int*    pos1 = (int*)   carve((size_t)N_DST1 * 4);
    int*    csr1 = (int*)   carve((size_t)E1 * 4);
    ushort* hN1b = (ushort*)carve((size_t)N_DST1 * FEAT * 2);
    ushort* hb   = (ushort*)carve((size_t)N_DST1 * FEAT * 2);
    u8*     hq   = (u8*)    carve((size_t)N_DST1 * FEAT);
    int*    off2 = (int*)   carve((size_t)(N_DST2 + 1) * 4);
    int*    pos2 = (int*)   carve((size_t)N_DST2 * 4);
    int*    csr2 = (int*)   carve((size_t)E2 * 4);
    ushort* hN2b = (ushort*)carve((size_t)N_DST2 * FEAT * 2);
    ushort* W1T  = (ushort*)carve((size_t)256 * 512 * 2);
    ushort* W2T  = (ushort*)carve((size_t)64 * 512 * 2);
    ushort* xb = (ushort*)carve((size_t)N_DST1 * FEAT * 2);
    size_t q_bytes = (size_t)N_SRC1 * FEAT;           // 1B per element
    bool fp8path = (o + q_bytes) <= ws_size;
    u32* xq = fp8path ? (u32*)carve(q_bytes) : nullptr;

    // ---- fused prep: x->fp8(all)+bf16(head) + degree count (both graphs) ----
    (void)hipMemsetAsync(degs, 0, (size_t)(N_DST1 + N_DST2) * 4, stream);
    {
        int n8  = (fp8path ? N_SRC1 : N_DST1) * FEAT / 8;
        int n8h = N_DST1 * FEAT / 8;
        int tot = n8 + (E1 >> 2) + (E2 >> 2) + (E1 & 3) + (E2 & 3);
        prep_kernel<<<(tot + 255) / 256, 256, 0, stream>>>(
            x, xb, xq, n8, n8h, dst1, E1, deg1, dst2, E2, deg2);
    }
    // ---- fused dual scan + W transposes ----
    scan_wt_kernel<<<514, 1024, 0, stream>>>(deg1, N_DST1, off1, pos1,
                                             deg2, N_DST2, off2, pos2,
                                             W1, W1T, W2, W2T);
    // ---- scatter (both graphs), 4 edges/thread ----
    {
        int tot = (E1 >> 2) + (E2 >> 2) + (E1 & 3) + (E2 & 3);
        scatter_csr2_kernel<<<(tot + 255) / 256, 256, 0, stream>>>(
            src1, dst1, E1, pos1, csr1, src2, dst2, E2, pos2, csr2);
    }

    if (fp8path) {
        // ---- layer 1: XCD-chunked fp8 aggregate + GEMM (writes bf16 h + fp8 h) ----
        int nblk = 8 * ((N_DST1 + 255) / 256);
        seg_mean_fp8_chunked_kernel<<<nblk, 256, 0, stream>>>(
            (const u8*)xq, off1, csr1, hN1b, N_DST1);
        gemm_mfma_kernel<128, 256, 2, 4, true, true, true><<<dim3(1, (N_DST1 + 127) / 128), 512, 0, stream>>>(
            xb, hN1b, W1T, b1, hb, nullptr, hq, N_DST1, 256);

        // ---- layer 2: fp8 aggregate (L2-resident) + GEMM (f32 out) ----
        seg_mean_fp8_kernel<<<(N_DST2 + 7) / 8, 512, 0, stream>>>(
            (const u32*)hq, off2, csr2, hN2b, N_DST2);
        gemm_mfma_kernel<64, 64, 2, 2, false, false, false><<<dim3(1, (N_DST2 + 63) / 64), 256, 0, stream>>>(
            hb, hN2b, W2T, b2, nullptr, out, nullptr, N_DST2, 64);
    } else {
        seg_mean_f32_kernel<<<N_DST1, 64, 0, stream>>>(x, off1, csr1, hN1b);
        gemm_mfma_kernel<128, 256, 2, 4, true, true, false><<<dim3(1, (N_DST1 + 127) / 128), 512, 0, stream>>>(
            xb, hN1b, W1T, b1, hb, nullptr, nullptr, N_DST1, 256);
        seg_mean_bf16_kernel<<<(N_DST2 + 7) / 8, 512, 0, stream>>>(hb, off2, csr2, hN2b, N_DST2);
        gemm_mfma_kernel<64, 64, 2, 2, false, false, false><<<dim3(1, (N_DST2 + 63) / 64), 256, 0, stream>>>(
            hb, hN2b, W2T, b2, nullptr, out, nullptr, N_DST2, 64);
    }
}

// Round 11
// 298.375 us; speedup vs baseline: 1.4548x; 1.4548x over previous
//
#include <hip/hip_runtime.h>
#include <hip/hip_bf16.h>

#define N_DST1 50000
#define N_DST2 10000
#define FEAT   256

typedef unsigned int u32;
typedef unsigned char u8;
typedef __attribute__((ext_vector_type(4))) float f32x4;
typedef __attribute__((ext_vector_type(8))) short bf16x8;

__device__ __forceinline__ ushort f2bf(float f) {
    u32 u = __float_as_uint(f);
    u32 r = (u + 0x7FFFu + ((u >> 16) & 1u)) >> 16;
    return (ushort)r;
}
__device__ __forceinline__ float bf2f(ushort u) {
    return __uint_as_float(((u32)u) << 16);
}
__device__ __forceinline__ u8 f2fp8(float f) {
    u32 pk = __builtin_amdgcn_cvt_pk_fp8_f32(f, f, 0, false);
    return (u8)(pk & 0xFF);
}

__device__ __forceinline__ void gload_lds16(const void* g, void* l) {
    __builtin_amdgcn_global_load_lds(
        (const __attribute__((address_space(1))) u32*)g,
        (__attribute__((address_space(3))) u32*)l, 16, 0, 0);
}

// ---------------- fused prep: x -> fp8(all rows) + bf16(head rows) + degree count ----------------
__global__ __launch_bounds__(256) void prep_kernel(
    const float* __restrict__ x, ushort* __restrict__ xb, u32* __restrict__ xq,
    int n8, int n8h,
    const int* __restrict__ dst1, int E1, int* __restrict__ deg1,
    const int* __restrict__ dst2, int E2, int* __restrict__ deg2)
{
    int gid = blockIdx.x * blockDim.x + threadIdx.x;
    if (gid < n8) {
        const f32x4* p = (const f32x4*)x + (size_t)gid * 2;
        f32x4 a = __builtin_nontemporal_load(p);
        f32x4 b = __builtin_nontemporal_load(p + 1);
        if (xq) {
            u32 w0 = 0, w1 = 0;
            w0 = __builtin_amdgcn_cvt_pk_fp8_f32(a.x, a.y, w0, false);
            w0 = __builtin_amdgcn_cvt_pk_fp8_f32(a.z, a.w, w0, true);
            w1 = __builtin_amdgcn_cvt_pk_fp8_f32(b.x, b.y, w1, false);
            w1 = __builtin_amdgcn_cvt_pk_fp8_f32(b.z, b.w, w1, true);
            uint2 wv; wv.x = w0; wv.y = w1;
            *((uint2*)xq + gid) = wv;
        }
        if (gid < n8h) {
            ushort4 lo = make_ushort4(f2bf(a.x), f2bf(a.y), f2bf(a.z), f2bf(a.w));
            ushort4 hi = make_ushort4(f2bf(b.x), f2bf(b.y), f2bf(b.z), f2bf(b.w));
            ushort4* q = (ushort4*)xb + (size_t)gid * 2;
            q[0] = lo; q[1] = hi;
        }
        return;
    }
    int e = gid - n8;
    int e14 = E1 >> 2, e24 = E2 >> 2;
    if (e < e14) {
        int4 d4 = reinterpret_cast<const int4*>(dst1)[e];
        atomicAdd(&deg1[d4.x], 1); atomicAdd(&deg1[d4.y], 1);
        atomicAdd(&deg1[d4.z], 1); atomicAdd(&deg1[d4.w], 1);
        return;
    }
    e -= e14;
    if (e < e24) {
        int4 d4 = reinterpret_cast<const int4*>(dst2)[e];
        atomicAdd(&deg2[d4.x], 1); atomicAdd(&deg2[d4.y], 1);
        atomicAdd(&deg2[d4.z], 1); atomicAdd(&deg2[d4.w], 1);
        return;
    }
    e -= e24;
    int r1 = E1 & 3;
    if (e < r1) { atomicAdd(&deg1[dst1[E1 - r1 + e]], 1); return; }
    e -= r1;
    int r2 = E2 & 3;
    if (e < r2) { atomicAdd(&deg2[dst2[E2 - r2 + e]], 1); return; }
}

// ---------------- fused: dual exclusive scan (blocks 0,1) + W transposes (blocks 2..513) ----------------
__global__ __launch_bounds__(1024) void scan_wt_kernel(
    const int* __restrict__ degA, int nA, int* __restrict__ offA, int* __restrict__ posA,
    const int* __restrict__ degB, int nB, int* __restrict__ offB, int* __restrict__ posB,
    const float* __restrict__ W1, ushort* __restrict__ W1T,
    const float* __restrict__ W2, ushort* __restrict__ W2T)
{
    if (blockIdx.x >= 2) {
        int k = blockIdx.x - 2;           // 512 k-rows
        int t = threadIdx.x;
        if (t < 256) W1T[(size_t)t * 512 + k] = f2bf(W1[(size_t)k * 256 + t]);
        else if (t < 320) {
            int n = t - 256;
            W2T[(size_t)n * 512 + k] = f2bf(W2[(size_t)k * 64 + n]);
        }
        return;
    }
    const int* deg = (blockIdx.x == 0) ? degA : degB;
    int*       off = (blockIdx.x == 0) ? offA : offB;
    int*       pos = (blockIdx.x == 0) ? posA : posB;
    int n = (blockIdx.x == 0) ? nA : nB;
    int n4 = n >> 2;

    __shared__ int wsum[16];
    __shared__ int carry_s;
    int t = threadIdx.x;
    int lane = t & 63, wid = t >> 6;
    if (t == 0) carry_s = 0;
    __syncthreads();
    for (int base = 0; base < n4; base += 1024) {
        int i = base + t;
        int4 v = make_int4(0, 0, 0, 0);
        if (i < n4) v = reinterpret_cast<const int4*>(deg)[i];
        int tot = v.x + v.y + v.z + v.w;
        int s = tot;
        #pragma unroll
        for (int d = 1; d < 64; d <<= 1) {
            int u = __shfl_up(s, d, 64);
            if (lane >= d) s += u;
        }
        if (lane == 63) wsum[wid] = s;
        __syncthreads();
        if (wid == 0 && lane < 16) {
            int ws = wsum[lane];
            #pragma unroll
            for (int d = 1; d < 16; d <<= 1) {
                int u = __shfl_up(ws, d, 64);
                if (lane >= d) ws += u;
            }
            wsum[lane] = ws;
        }
        __syncthreads();
        int waveoff = (wid == 0) ? 0 : wsum[wid - 1];
        int carry = carry_s;
        int base0 = carry + waveoff + s - tot;
        if (i < n4) {
            int4 e;
            e.x = base0;
            e.y = base0 + v.x;
            e.z = base0 + v.x + v.y;
            e.w = base0 + v.x + v.y + v.z;
            reinterpret_cast<int4*>(off)[i] = e;
            reinterpret_cast<int4*>(pos)[i] = e;
        }
        __syncthreads();
        if (t == 0) carry_s = carry + wsum[15];
        __syncthreads();
    }
    if (t == 0) off[n] = carry_s;
}

// ---------------- merged scatter (both graphs), 4 edges/thread ----------------
__global__ void scatter_csr2_kernel(const int* __restrict__ src1, const int* __restrict__ dst1,
                                    int E1, int* __restrict__ pos1, int* __restrict__ csr1,
                                    const int* __restrict__ src2, const int* __restrict__ dst2,
                                    int E2, int* __restrict__ pos2, int* __restrict__ csr2) {
    int e = blockIdx.x * blockDim.x + threadIdx.x;
    int e14 = E1 >> 2, e24 = E2 >> 2;
    if (e < e14) {
        int4 s4 = reinterpret_cast<const int4*>(src1)[e];
        int4 d4 = reinterpret_cast<const int4*>(dst1)[e];
        csr1[atomicAdd(&pos1[d4.x], 1)] = s4.x;
        csr1[atomicAdd(&pos1[d4.y], 1)] = s4.y;
        csr1[atomicAdd(&pos1[d4.z], 1)] = s4.z;
        csr1[atomicAdd(&pos1[d4.w], 1)] = s4.w;
        return;
    }
    e -= e14;
    if (e < e24) {
        int4 s4 = reinterpret_cast<const int4*>(src2)[e];
        int4 d4 = reinterpret_cast<const int4*>(dst2)[e];
        csr2[atomicAdd(&pos2[d4.x], 1)] = s4.x;
        csr2[atomicAdd(&pos2[d4.y], 1)] = s4.y;
        csr2[atomicAdd(&pos2[d4.z], 1)] = s4.z;
        csr2[atomicAdd(&pos2[d4.w], 1)] = s4.w;
        return;
    }
    e -= e24;
    int r1 = E1 & 3;
    if (e < r1) {
        int i = E1 - r1 + e;
        csr1[atomicAdd(&pos1[dst1[i]], 1)] = src1[i];
        return;
    }
    e -= r1;
    int r2 = E2 & 3;
    if (e < r2) {
        int i = E2 - r2 + e;
        csr2[atomicAdd(&pos2[dst2[i]], 1)] = src2[i];
        return;
    }
}

// ---------------- segment mean over fp8 rows: 8 edges in flight/wave, 16 lanes x 16B per row ----------------
__global__ __launch_bounds__(512) void seg_mean_fp8_kernel(
    const u32* __restrict__ Xq, const int* __restrict__ off,
    const int* __restrict__ csr, ushort* __restrict__ out, int ndst)
{
    int wid = threadIdx.x >> 6;
    int d = blockIdx.x * 8 + wid;
    if (d >= ndst) return;
    int l = threadIdx.x & 63;
    int sub = l >> 4;                 // edge slot within quad
    int lg = l & 15;                  // 16 feats (16B) per lane
    int beg = off[d], end = off[d + 1];
    float acc[16];
    #pragma unroll
    for (int q = 0; q < 16; ++q) acc[q] = 0.f;
    for (int j = beg; j < end; j += 8) {
        int i0 = j + sub, i1 = j + 4 + sub;
        int r0 = csr[min(i0, end - 1)];
        int r1 = csr[min(i1, end - 1)];
        uint4 v0 = *reinterpret_cast<const uint4*>(Xq + (size_t)r0 * 64 + lg * 4);
        uint4 v1 = *reinterpret_cast<const uint4*>(Xq + (size_t)r1 * 64 + lg * 4);
        float m0 = (i0 < end) ? 1.f : 0.f;
        float m1 = (i1 < end) ? 1.f : 0.f;
        u32 w0[4] = {v0.x, v0.y, v0.z, v0.w};
        u32 w1[4] = {v1.x, v1.y, v1.z, v1.w};
        #pragma unroll
        for (int w = 0; w < 4; ++w) {
            auto a01 = __builtin_amdgcn_cvt_pk_f32_fp8(w0[w], false);
            auto a23 = __builtin_amdgcn_cvt_pk_f32_fp8(w0[w], true);
            auto b01 = __builtin_amdgcn_cvt_pk_f32_fp8(w1[w], false);
            auto b23 = __builtin_amdgcn_cvt_pk_f32_fp8(w1[w], true);
            acc[w * 4 + 0] += m0 * a01[0] + m1 * b01[0];
            acc[w * 4 + 1] += m0 * a01[1] + m1 * b01[1];
            acc[w * 4 + 2] += m0 * a23[0] + m1 * b23[0];
            acc[w * 4 + 3] += m0 * a23[1] + m1 * b23[1];
        }
    }
    #pragma unroll
    for (int q = 0; q < 16; ++q) {
        acc[q] += __shfl_xor(acc[q], 16);
        acc[q] += __shfl_xor(acc[q], 32);
    }
    if (l < 16) {
        float sc = 1.0f / (float)max(end - beg, 1);
        bf16x8 o0, o1;
        #pragma unroll
        for (int q = 0; q < 8; ++q) {
            o0[q] = (short)f2bf(acc[q] * sc);
            o1[q] = (short)f2bf(acc[8 + q] * sc);
        }
        ushort* base = out + (size_t)d * FEAT + lg * 16;
        *reinterpret_cast<bf16x8*>(base) = o0;
        *reinterpret_cast<bf16x8*>(base + 8) = o1;
    }
}

// ---------------- segment mean (bf16 gather) — fallback ----------------
__global__ __launch_bounds__(512) void seg_mean_bf16_kernel(
    const ushort* __restrict__ X, const int* __restrict__ off,
    const int* __restrict__ csr, ushort* __restrict__ out, int ndst)
{
    int wid = threadIdx.x >> 6;
    int d = blockIdx.x * 8 + wid;
    if (d >= ndst) return;
    int l = threadIdx.x & 63;
    int half = l >> 5;
    int f8 = (l & 31) * 8;
    int beg = off[d], end = off[d + 1];
    float acc[8] = {0.f, 0.f, 0.f, 0.f, 0.f, 0.f, 0.f, 0.f};
    for (int j = beg; j < end; j += 8) {
        #pragma unroll
        for (int p = 0; p < 4; ++p) {
            int idx = j + p * 2 + half;
            int r = csr[min(idx, end - 1)];
            bf16x8 v = *reinterpret_cast<const bf16x8*>(&X[(size_t)r * FEAT + f8]);
            float m = (idx < end) ? 1.f : 0.f;
            #pragma unroll
            for (int q = 0; q < 8; ++q) acc[q] += m * bf2f((ushort)v[q]);
        }
    }
    #pragma unroll
    for (int q = 0; q < 8; ++q) acc[q] += __shfl_xor(acc[q], 32);
    if (l < 32) {
        float sc = 1.0f / (float)max(end - beg, 1);
        bf16x8 ov;
        #pragma unroll
        for (int q = 0; q < 8; ++q) ov[q] = (short)f2bf(acc[q] * sc);
        *reinterpret_cast<bf16x8*>(&out[(size_t)d * FEAT + f8]) = ov;
    }
}

// ---------------- f32-gather fallback (small ws) ----------------
__global__ void seg_mean_f32_kernel(const float* __restrict__ X, const int* __restrict__ off,
                                    const int* __restrict__ csr, ushort* __restrict__ out) {
    int d = blockIdx.x;
    int t = threadIdx.x;
    int beg = off[d], end = off[d + 1];
    float a0 = 0.f, a1 = 0.f, a2 = 0.f, a3 = 0.f;
    for (int j = beg; j < end; ++j) {
        int s = csr[j];
        float4 v = *reinterpret_cast<const float4*>(&X[(size_t)s * FEAT + t * 4]);
        a0 += v.x; a1 += v.y; a2 += v.z; a3 += v.w;
    }
    float sc = 1.0f / (float)max(end - beg, 1);
    ushort4 o = make_ushort4(f2bf(a0 * sc), f2bf(a1 * sc), f2bf(a2 * sc), f2bf(a3 * sc));
    *reinterpret_cast<ushort4*>(&out[(size_t)d * FEAT + t * 4]) = o;
}

// ---------------- bf16 MFMA GEMM: C = concat(A0,A1) @ BT^T + bias (+ optional fp8 copy) ----------------
template<int BM, int BN, int WGM, int WGN, bool RELU, bool OBF16, bool WQ8>
__global__ __launch_bounds__(WGM * WGN * 64)
void gemm_mfma_kernel(const ushort* __restrict__ A0, const ushort* __restrict__ A1,
                      const ushort* __restrict__ BT, const float* __restrict__ bias,
                      ushort* __restrict__ Cb, float* __restrict__ Cf, u8* __restrict__ Cq,
                      int M, int Nfull) {
    constexpr int NWAVE = WGM * WGN;
    constexpr int WM = BM / WGM;
    constexpr int WN = BN / WGN;
    constexpr int MF = WM / 16;
    constexpr int NF = WN / 16;
    constexpr int ACH = BM / 16;
    constexpr int BCH = BN / 16;

    __shared__ ushort Al[2][BM][32];
    __shared__ ushort Bl[2][BN][32];

    const int t = threadIdx.x;
    const int lane = t & 63;
    const int wid = t >> 6;
    const int wm = wid / WGN, wn = wid % WGN;
    const int lr = lane & 15, grp = lane >> 4;
    const int rowBase = blockIdx.y * BM;
    const int colBase = blockIdx.x * BN;

    f32x4 acc[MF][NF];
    #pragma unroll
    for (int m = 0; m < MF; ++m)
        #pragma unroll
        for (int n = 0; n < NF; ++n)
            acc[m][n] = (f32x4){0.f, 0.f, 0.f, 0.f};

    auto stage = [&](int buf, int kt) {
        const ushort* Asrc = (kt < 8) ? A0 : A1;
        const int kcol = (kt * 32) & 255;
        #pragma unroll
        for (int ch = wid; ch < ACH; ch += NWAVE) {
            int r = ch * 16 + (lane >> 2);
            int rg = min(rowBase + r, M - 1);
            int c = lane & 3;
            int ksw = (c ^ (r & 3)) * 8;
            gload_lds16(&Asrc[(size_t)rg * 256 + kcol + ksw], &Al[buf][ch * 16][0]);
        }
        #pragma unroll
        for (int ch = wid; ch < BCH; ch += NWAVE) {
            int r = ch * 16 + (lane >> 2);
            int c = lane & 3;
            int ksw = (c ^ (r & 3)) * 8;
            gload_lds16(&BT[(size_t)(colBase + r) * 512 + kt * 32 + ksw], &Bl[buf][ch * 16][0]);
        }
    };

    stage(0, 0);
    __syncthreads();

    int buf = 0;
    for (int kt = 0; kt < 16; ++kt) {
        if (kt + 1 < 16) stage(buf ^ 1, kt + 1);
        bf16x8 af[MF], bfr[NF];
        #pragma unroll
        for (int m = 0; m < MF; ++m) {
            int r = wm * WM + m * 16 + lr;
            af[m] = *reinterpret_cast<const bf16x8*>(
                (const char*)&Al[buf][0][0] + r * 64 + ((grp ^ (r & 3)) << 4));
        }
        #pragma unroll
        for (int n = 0; n < NF; ++n) {
            int r = wn * WN + n * 16 + lr;
            bfr[n] = *reinterpret_cast<const bf16x8*>(
                (const char*)&Bl[buf][0][0] + r * 64 + ((grp ^ (r & 3)) << 4));
        }
        #pragma unroll
        for (int m = 0; m < MF; ++m)
            #pragma unroll
            for (int n = 0; n < NF; ++n)
                acc[m][n] = __builtin_amdgcn_mfma_f32_16x16x32_bf16(af[m], bfr[n], acc[m][n], 0, 0, 0);
        __syncthreads();
        buf ^= 1;
    }

    #pragma unroll
    for (int m = 0; m < MF; ++m) {
        #pragma unroll
        for (int q = 0; q < 4; ++q) {
            int rowg = rowBase + wm * WM + m * 16 + grp * 4 + q;
            if (rowg >= M) continue;
            #pragma unroll
            for (int n = 0; n < NF; ++n) {
                int colg = colBase + wn * WN + n * 16 + lr;
                float v = acc[m][n][q] + bias[colg];
                if (RELU) v = fmaxf(v, 0.f);
                if (OBF16) Cb[(size_t)rowg * Nfull + colg] = f2bf(v);
                else       Cf[(size_t)rowg * Nfull + colg] = v;
                if (WQ8)   Cq[(size_t)rowg * Nfull + colg] = f2fp8(v);
            }
        }
    }
}

extern "C" void kernel_launch(void* const* d_in, const int* in_sizes, int n_in,
                              void* d_out, int out_size, void* d_ws, size_t ws_size,
                              hipStream_t stream) {
    const float* x  = (const float*)d_in[0];
    const float* W1 = (const float*)d_in[1];
    const float* b1 = (const float*)d_in[2];
    const float* W2 = (const float*)d_in[3];
    const float* b2 = (const float*)d_in[4];
    const int* src1 = (const int*)d_in[5];
    const int* dst1 = (const int*)d_in[6];
    const int* src2 = (const int*)d_in[7];
    const int* dst2 = (const int*)d_in[8];
    const int E1 = in_sizes[5];
    const int E2 = in_sizes[7];
    const int N_SRC1 = in_sizes[0] / FEAT;   // 200000
    float* out = (float*)d_out;

    char* ws = (char*)d_ws;
    size_t o = 0;
    auto carve = [&](size_t bytes) { char* p = ws + o; o = (o + bytes + 255) & ~(size_t)255; return p; };
    int*    degs = (int*)   carve((size_t)(N_DST1 + N_DST2) * 4);
    int*    deg1 = degs;
    int*    deg2 = degs + N_DST1;
    int*    off1 = (int*)   carve((size_t)(N_DST1 + 1) * 4);
    int*    pos1 = (int*)   carve((size_t)N_DST1 * 4);
    int*    csr1 = (int*)   carve((size_t)E1 * 4);
    ushort* hN1b = (ushort*)carve((size_t)N_DST1 * FEAT * 2);
    ushort* hb   = (ushort*)carve((size_t)N_DST1 * FEAT * 2);
    u8*     hq   = (u8*)    carve((size_t)N_DST1 * FEAT);
    int*    off2 = (int*)   carve((size_t)(N_DST2 + 1) * 4);
    int*    pos2 = (int*)   carve((size_t)N_DST2 * 4);
    int*    csr2 = (int*)   carve((size_t)E2 * 4);
    ushort* hN2b = (ushort*)carve((size_t)N_DST2 * FEAT * 2);
    ushort* W1T  = (ushort*)carve((size_t)256 * 512 * 2);
    ushort* W2T  = (ushort*)carve((size_t)64 * 512 * 2);
    ushort* xb = (ushort*)carve((size_t)N_DST1 * FEAT * 2);
    size_t q_bytes = (size_t)N_SRC1 * FEAT;           // 1B per element
    bool fp8path = (o + q_bytes) <= ws_size;
    u32* xq = fp8path ? (u32*)carve(q_bytes) : nullptr;

    // ---- fused prep: x->fp8(all)+bf16(head) + degree count (both graphs) ----
    (void)hipMemsetAsync(degs, 0, (size_t)(N_DST1 + N_DST2) * 4, stream);
    {
        int n8  = (fp8path ? N_SRC1 : N_DST1) * FEAT / 8;
        int n8h = N_DST1 * FEAT / 8;
        int tot = n8 + (E1 >> 2) + (E2 >> 2) + (E1 & 3) + (E2 & 3);
        prep_kernel<<<(tot + 255) / 256, 256, 0, stream>>>(
            x, xb, xq, n8, n8h, dst1, E1, deg1, dst2, E2, deg2);
    }
    // ---- fused dual scan + W transposes ----
    scan_wt_kernel<<<514, 1024, 0, stream>>>(deg1, N_DST1, off1, pos1,
                                             deg2, N_DST2, off2, pos2,
                                             W1, W1T, W2, W2T);
    // ---- scatter (both graphs), 4 edges/thread ----
    {
        int tot = (E1 >> 2) + (E2 >> 2) + (E1 & 3) + (E2 & 3);
        scatter_csr2_kernel<<<(tot + 255) / 256, 256, 0, stream>>>(
            src1, dst1, E1, pos1, csr1, src2, dst2, E2, pos2, csr2);
    }

    if (fp8path) {
        // ---- layer 1: fp8 aggregate (wave-per-dst) + GEMM (writes bf16 h + fp8 h) ----
        seg_mean_fp8_kernel<<<(N_DST1 + 7) / 8, 512, 0, stream>>>(
            xq, off1, csr1, hN1b, N_DST1);
        gemm_mfma_kernel<128, 256, 2, 4, true, true, true><<<dim3(1, (N_DST1 + 127) / 128), 512, 0, stream>>>(
            xb, hN1b, W1T, b1, hb, nullptr, hq, N_DST1, 256);

        // ---- layer 2: fp8 aggregate (L2-resident) + GEMM (f32 out) ----
        seg_mean_fp8_kernel<<<(N_DST2 + 7) / 8, 512, 0, stream>>>(
            (const u32*)hq, off2, csr2, hN2b, N_DST2);
        gemm_mfma_kernel<64, 64, 2, 2, false, false, false><<<dim3(1, (N_DST2 + 63) / 64), 256, 0, stream>>>(
            hb, hN2b, W2T, b2, nullptr, out, nullptr, N_DST2, 64);
    } else {
        seg_mean_f32_kernel<<<N_DST1, 64, 0, stream>>>(x, off1, csr1, hN1b);
        gemm_mfma_kernel<128, 256, 2, 4, true, true, false><<<dim3(1, (N_DST1 + 127) / 128), 512, 0, stream>>>(
            xb, hN1b, W1T, b1, hb, nullptr, nullptr, N_DST1, 256);
        seg_mean_bf16_kernel<<<(N_DST2 + 7) / 8, 512, 0, stream>>>(hb, off2, csr2, hN2b, N_DST2);
        gemm_mfma_kernel<64, 64, 2, 2, false, false, false><<<dim3(1, (N_DST2 + 63) / 64), 256, 0, stream>>>(
            hb, hN2b, W2T, b2, nullptr, out, nullptr, N_DST2, 64);
    }
}

// Round 12
// 297.721 us; speedup vs baseline: 1.4580x; 1.0022x over previous
//
#include <hip/hip_runtime.h>
#include <hip/hip_bf16.h>

#define N_DST1 50000
#define N_DST2 10000
#define FEAT   256

typedef unsigned int u32;
typedef unsigned char u8;
typedef __attribute__((ext_vector_type(4))) float f32x4;
typedef __attribute__((ext_vector_type(8))) short bf16x8;

__device__ __forceinline__ ushort f2bf(float f) {
    u32 u = __float_as_uint(f);
    u32 r = (u + 0x7FFFu + ((u >> 16) & 1u)) >> 16;
    return (ushort)r;
}
__device__ __forceinline__ float bf2f(ushort u) {
    return __uint_as_float(((u32)u) << 16);
}
__device__ __forceinline__ u8 f2fp8(float f) {
    u32 pk = __builtin_amdgcn_cvt_pk_fp8_f32(f, f, 0, false);
    return (u8)(pk & 0xFF);
}

__device__ __forceinline__ void gload_lds16(const void* g, void* l) {
    __builtin_amdgcn_global_load_lds(
        (const __attribute__((address_space(1))) u32*)g,
        (__attribute__((address_space(3))) u32*)l, 16, 0, 0);
}

// ---------------- fused prep: x->fp8(all)+bf16(head) + degree count + W transposes ----------------
__global__ __launch_bounds__(256) void prep_kernel(
    const float* __restrict__ x, ushort* __restrict__ xb, u32* __restrict__ xq,
    int n8, int n8h,
    const int* __restrict__ dst1, int E1, int* __restrict__ deg1,
    const int* __restrict__ dst2, int E2, int* __restrict__ deg2,
    const float* __restrict__ W1, ushort* __restrict__ W1T,
    const float* __restrict__ W2, ushort* __restrict__ W2T)
{
    int gid = blockIdx.x * blockDim.x + threadIdx.x;
    if (gid < n8) {
        const f32x4* p = (const f32x4*)x + (size_t)gid * 2;
        f32x4 a = __builtin_nontemporal_load(p);
        f32x4 b = __builtin_nontemporal_load(p + 1);
        if (xq) {
            u32 w0 = 0, w1 = 0;
            w0 = __builtin_amdgcn_cvt_pk_fp8_f32(a.x, a.y, w0, false);
            w0 = __builtin_amdgcn_cvt_pk_fp8_f32(a.z, a.w, w0, true);
            w1 = __builtin_amdgcn_cvt_pk_fp8_f32(b.x, b.y, w1, false);
            w1 = __builtin_amdgcn_cvt_pk_fp8_f32(b.z, b.w, w1, true);
            uint2 wv; wv.x = w0; wv.y = w1;
            *((uint2*)xq + gid) = wv;
        }
        if (gid < n8h) {
            ushort4 lo = make_ushort4(f2bf(a.x), f2bf(a.y), f2bf(a.z), f2bf(a.w));
            ushort4 hi = make_ushort4(f2bf(b.x), f2bf(b.y), f2bf(b.z), f2bf(b.w));
            ushort4* q = (ushort4*)xb + (size_t)gid * 2;
            q[0] = lo; q[1] = hi;
        }
        return;
    }
    int e = gid - n8;
    int e14 = E1 >> 2, e24 = E2 >> 2;
    if (e < e14) {
        int4 d4 = reinterpret_cast<const int4*>(dst1)[e];
        atomicAdd(&deg1[d4.x], 1); atomicAdd(&deg1[d4.y], 1);
        atomicAdd(&deg1[d4.z], 1); atomicAdd(&deg1[d4.w], 1);
        return;
    }
    e -= e14;
    if (e < e24) {
        int4 d4 = reinterpret_cast<const int4*>(dst2)[e];
        atomicAdd(&deg2[d4.x], 1); atomicAdd(&deg2[d4.y], 1);
        atomicAdd(&deg2[d4.z], 1); atomicAdd(&deg2[d4.w], 1);
        return;
    }
    e -= e24;
    int r1 = E1 & 3;
    if (e < r1) { atomicAdd(&deg1[dst1[E1 - r1 + e]], 1); return; }
    e -= r1;
    int r2 = E2 & 3;
    if (e < r2) { atomicAdd(&deg2[dst2[E2 - r2 + e]], 1); return; }
    e -= r2;
    if (e < 512 * 256) {
        int k = e >> 8, n = e & 255;       // consecutive gid -> consecutive n (coalesced read)
        W1T[(size_t)n * 512 + k] = f2bf(W1[(size_t)k * 256 + n]);
        return;
    }
    e -= 512 * 256;
    if (e < 512 * 64) {
        int k = e >> 6, n = e & 63;
        W2T[(size_t)n * 512 + k] = f2bf(W2[(size_t)k * 64 + n]);
        return;
    }
}

// ---------------- dual exclusive scan: block 0 -> graph1, block 1 -> graph2 ----------------
__global__ __launch_bounds__(1024) void scan_kernel(
    const int* __restrict__ degA, int nA, int* __restrict__ offA, int* __restrict__ posA,
    const int* __restrict__ degB, int nB, int* __restrict__ offB, int* __restrict__ posB)
{
    const int* deg = (blockIdx.x == 0) ? degA : degB;
    int*       off = (blockIdx.x == 0) ? offA : offB;
    int*       pos = (blockIdx.x == 0) ? posA : posB;
    int n = (blockIdx.x == 0) ? nA : nB;
    int n4 = n >> 2;

    __shared__ int wsum[16];
    __shared__ int carry_s;
    int t = threadIdx.x;
    int lane = t & 63, wid = t >> 6;
    if (t == 0) carry_s = 0;
    __syncthreads();
    for (int base = 0; base < n4; base += 1024) {
        int i = base + t;
        int4 v = make_int4(0, 0, 0, 0);
        if (i < n4) v = reinterpret_cast<const int4*>(deg)[i];
        int tot = v.x + v.y + v.z + v.w;
        int s = tot;
        #pragma unroll
        for (int d = 1; d < 64; d <<= 1) {
            int u = __shfl_up(s, d, 64);
            if (lane >= d) s += u;
        }
        if (lane == 63) wsum[wid] = s;
        __syncthreads();
        if (wid == 0 && lane < 16) {
            int ws = wsum[lane];
            #pragma unroll
            for (int d = 1; d < 16; d <<= 1) {
                int u = __shfl_up(ws, d, 64);
                if (lane >= d) ws += u;
            }
            wsum[lane] = ws;
        }
        __syncthreads();
        int waveoff = (wid == 0) ? 0 : wsum[wid - 1];
        int carry = carry_s;
        int base0 = carry + waveoff + s - tot;
        if (i < n4) {
            int4 e;
            e.x = base0;
            e.y = base0 + v.x;
            e.z = base0 + v.x + v.y;
            e.w = base0 + v.x + v.y + v.z;
            reinterpret_cast<int4*>(off)[i] = e;
            reinterpret_cast<int4*>(pos)[i] = e;
        }
        __syncthreads();
        if (t == 0) carry_s = carry + wsum[15];
        __syncthreads();
    }
    if (t == 0) off[n] = carry_s;
}

// ---------------- merged scatter (both graphs), 4 edges/thread ----------------
__global__ void scatter_csr2_kernel(const int* __restrict__ src1, const int* __restrict__ dst1,
                                    int E1, int* __restrict__ pos1, int* __restrict__ csr1,
                                    const int* __restrict__ src2, const int* __restrict__ dst2,
                                    int E2, int* __restrict__ pos2, int* __restrict__ csr2) {
    int e = blockIdx.x * blockDim.x + threadIdx.x;
    int e14 = E1 >> 2, e24 = E2 >> 2;
    if (e < e14) {
        int4 s4 = reinterpret_cast<const int4*>(src1)[e];
        int4 d4 = reinterpret_cast<const int4*>(dst1)[e];
        csr1[atomicAdd(&pos1[d4.x], 1)] = s4.x;
        csr1[atomicAdd(&pos1[d4.y], 1)] = s4.y;
        csr1[atomicAdd(&pos1[d4.z], 1)] = s4.z;
        csr1[atomicAdd(&pos1[d4.w], 1)] = s4.w;
        return;
    }
    e -= e14;
    if (e < e24) {
        int4 s4 = reinterpret_cast<const int4*>(src2)[e];
        int4 d4 = reinterpret_cast<const int4*>(dst2)[e];
        csr2[atomicAdd(&pos2[d4.x], 1)] = s4.x;
        csr2[atomicAdd(&pos2[d4.y], 1)] = s4.y;
        csr2[atomicAdd(&pos2[d4.z], 1)] = s4.z;
        csr2[atomicAdd(&pos2[d4.w], 1)] = s4.w;
        return;
    }
    e -= e24;
    int r1 = E1 & 3;
    if (e < r1) {
        int i = E1 - r1 + e;
        csr1[atomicAdd(&pos1[dst1[i]], 1)] = src1[i];
        return;
    }
    e -= r1;
    int r2 = E2 & 3;
    if (e < r2) {
        int i = E2 - r2 + e;
        csr2[atomicAdd(&pos2[dst2[i]], 1)] = src2[i];
        return;
    }
}

// ---------------- segment mean over fp8 rows: 8 edges in flight/wave, 16 lanes x 16B per row ----------------
__global__ __launch_bounds__(512) void seg_mean_fp8_kernel(
    const u32* __restrict__ Xq, const int* __restrict__ off,
    const int* __restrict__ csr, ushort* __restrict__ out, int ndst)
{
    int wid = threadIdx.x >> 6;
    int d = blockIdx.x * 8 + wid;
    if (d >= ndst) return;
    int l = threadIdx.x & 63;
    int sub = l >> 4;                 // edge slot within quad
    int lg = l & 15;                  // 16 feats (16B) per lane
    int beg = off[d], end = off[d + 1];
    float acc[16];
    #pragma unroll
    for (int q = 0; q < 16; ++q) acc[q] = 0.f;
    for (int j = beg; j < end; j += 8) {
        int i0 = j + sub, i1 = j + 4 + sub;
        int r0 = csr[min(i0, end - 1)];
        int r1 = csr[min(i1, end - 1)];
        uint4 v0 = *reinterpret_cast<const uint4*>(Xq + (size_t)r0 * 64 + lg * 4);
        uint4 v1 = *reinterpret_cast<const uint4*>(Xq + (size_t)r1 * 64 + lg * 4);
        float m0 = (i0 < end) ? 1.f : 0.f;
        float m1 = (i1 < end) ? 1.f : 0.f;
        u32 w0[4] = {v0.x, v0.y, v0.z, v0.w};
        u32 w1[4] = {v1.x, v1.y, v1.z, v1.w};
        #pragma unroll
        for (int w = 0; w < 4; ++w) {
            auto a01 = __builtin_amdgcn_cvt_pk_f32_fp8(w0[w], false);
            auto a23 = __builtin_amdgcn_cvt_pk_f32_fp8(w0[w], true);
            auto b01 = __builtin_amdgcn_cvt_pk_f32_fp8(w1[w], false);
            auto b23 = __builtin_amdgcn_cvt_pk_f32_fp8(w1[w], true);
            acc[w * 4 + 0] += m0 * a01[0] + m1 * b01[0];
            acc[w * 4 + 1] += m0 * a01[1] + m1 * b01[1];
            acc[w * 4 + 2] += m0 * a23[0] + m1 * b23[0];
            acc[w * 4 + 3] += m0 * a23[1] + m1 * b23[1];
        }
    }
    #pragma unroll
    for (int q = 0; q < 16; ++q) {
        acc[q] += __shfl_xor(acc[q], 16);
        acc[q] += __shfl_xor(acc[q], 32);
    }
    if (l < 16) {
        float sc = 1.0f / (float)max(end - beg, 1);
        bf16x8 o0, o1;
        #pragma unroll
        for (int q = 0; q < 8; ++q) {
            o0[q] = (short)f2bf(acc[q] * sc);
            o1[q] = (short)f2bf(acc[8 + q] * sc);
        }
        ushort* base = out + (size_t)d * FEAT + lg * 16;
        *reinterpret_cast<bf16x8*>(base) = o0;
        *reinterpret_cast<bf16x8*>(base + 8) = o1;
    }
}

// ---------------- segment mean (bf16 gather) — fallback ----------------
__global__ __launch_bounds__(512) void seg_mean_bf16_kernel(
    const ushort* __restrict__ X, const int* __restrict__ off,
    const int* __restrict__ csr, ushort* __restrict__ out, int ndst)
{
    int wid = threadIdx.x >> 6;
    int d = blockIdx.x * 8 + wid;
    if (d >= ndst) return;
    int l = threadIdx.x & 63;
    int half = l >> 5;
    int f8 = (l & 31) * 8;
    int beg = off[d], end = off[d + 1];
    float acc[8] = {0.f, 0.f, 0.f, 0.f, 0.f, 0.f, 0.f, 0.f};
    for (int j = beg; j < end; j += 8) {
        #pragma unroll
        for (int p = 0; p < 4; ++p) {
            int idx = j + p * 2 + half;
            int r = csr[min(idx, end - 1)];
            bf16x8 v = *reinterpret_cast<const bf16x8*>(&X[(size_t)r * FEAT + f8]);
            float m = (idx < end) ? 1.f : 0.f;
            #pragma unroll
            for (int q = 0; q < 8; ++q) acc[q] += m * bf2f((ushort)v[q]);
        }
    }
    #pragma unroll
    for (int q = 0; q < 8; ++q) acc[q] += __shfl_xor(acc[q], 32);
    if (l < 32) {
        float sc = 1.0f / (float)max(end - beg, 1);
        bf16x8 ov;
        #pragma unroll
        for (int q = 0; q < 8; ++q) ov[q] = (short)f2bf(acc[q] * sc);
        *reinterpret_cast<bf16x8*>(&out[(size_t)d * FEAT + f8]) = ov;
    }
}

// ---------------- f32-gather fallback (small ws) ----------------
__global__ void seg_mean_f32_kernel(const float* __restrict__ X, const int* __restrict__ off,
                                    const int* __restrict__ csr, ushort* __restrict__ out) {
    int d = blockIdx.x;
    int t = threadIdx.x;
    int beg = off[d], end = off[d + 1];
    float a0 = 0.f, a1 = 0.f, a2 = 0.f, a3 = 0.f;
    for (int j = beg; j < end; ++j) {
        int s = csr[j];
        float4 v = *reinterpret_cast<const float4*>(&X[(size_t)s * FEAT + t * 4]);
        a0 += v.x; a1 += v.y; a2 += v.z; a3 += v.w;
    }
    float sc = 1.0f / (float)max(end - beg, 1);
    ushort4 o = make_ushort4(f2bf(a0 * sc), f2bf(a1 * sc), f2bf(a2 * sc), f2bf(a3 * sc));
    *reinterpret_cast<ushort4*>(&out[(size_t)d * FEAT + t * 4]) = o;
}

// ---------------- W [512][N] f32 -> WT [N][512] bf16 (fallback path only) ----------------
__global__ void cvt_wt2_kernel(const float* __restrict__ W1, ushort* __restrict__ W1T,
                               const float* __restrict__ W2, ushort* __restrict__ W2T) {
    int k = blockIdx.x;
    int t = threadIdx.x;
    if (t < 256) W1T[(size_t)t * 512 + k] = f2bf(W1[(size_t)k * 256 + t]);
    else if (t < 320) {
        int n = t - 256;
        W2T[(size_t)n * 512 + k] = f2bf(W2[(size_t)k * 64 + n]);
    }
}

// ---------------- bf16 MFMA GEMM: C = concat(A0,A1) @ BT^T + bias (+ optional fp8 copy) ----------------
template<int BM, int BN, int WGM, int WGN, bool RELU, bool OBF16, bool WQ8>
__global__ __launch_bounds__(WGM * WGN * 64)
void gemm_mfma_kernel(const ushort* __restrict__ A0, const ushort* __restrict__ A1,
                      const ushort* __restrict__ BT, const float* __restrict__ bias,
                      ushort* __restrict__ Cb, float* __restrict__ Cf, u8* __restrict__ Cq,
                      int M, int Nfull) {
    constexpr int NWAVE = WGM * WGN;
    constexpr int WM = BM / WGM;
    constexpr int WN = BN / WGN;
    constexpr int MF = WM / 16;
    constexpr int NF = WN / 16;
    constexpr int ACH = BM / 16;
    constexpr int BCH = BN / 16;

    __shared__ ushort Al[2][BM][32];
    __shared__ ushort Bl[2][BN][32];

    const int t = threadIdx.x;
    const int lane = t & 63;
    const int wid = t >> 6;
    const int wm = wid / WGN, wn = wid % WGN;
    const int lr = lane & 15, grp = lane >> 4;
    const int rowBase = blockIdx.y * BM;
    const int colBase = blockIdx.x * BN;

    f32x4 acc[MF][NF];
    #pragma unroll
    for (int m = 0; m < MF; ++m)
        #pragma unroll
        for (int n = 0; n < NF; ++n)
            acc[m][n] = (f32x4){0.f, 0.f, 0.f, 0.f};

    auto stage = [&](int buf, int kt) {
        const ushort* Asrc = (kt < 8) ? A0 : A1;
        const int kcol = (kt * 32) & 255;
        #pragma unroll
        for (int ch = wid; ch < ACH; ch += NWAVE) {
            int r = ch * 16 + (lane >> 2);
            int rg = min(rowBase + r, M - 1);
            int c = lane & 3;
            int ksw = (c ^ (r & 3)) * 8;
            gload_lds16(&Asrc[(size_t)rg * 256 + kcol + ksw], &Al[buf][ch * 16][0]);
        }
        #pragma unroll
        for (int ch = wid; ch < BCH; ch += NWAVE) {
            int r = ch * 16 + (lane >> 2);
            int c = lane & 3;
            int ksw = (c ^ (r & 3)) * 8;
            gload_lds16(&BT[(size_t)(colBase + r) * 512 + kt * 32 + ksw], &Bl[buf][ch * 16][0]);
        }
    };

    stage(0, 0);
    __syncthreads();

    int buf = 0;
    for (int kt = 0; kt < 16; ++kt) {
        if (kt + 1 < 16) stage(buf ^ 1, kt + 1);
        bf16x8 af[MF], bfr[NF];
        #pragma unroll
        for (int m = 0; m < MF; ++m) {
            int r = wm * WM + m * 16 + lr;
            af[m] = *reinterpret_cast<const bf16x8*>(
                (const char*)&Al[buf][0][0] + r * 64 + ((grp ^ (r & 3)) << 4));
        }
        #pragma unroll
        for (int n = 0; n < NF; ++n) {
            int r = wn * WN + n * 16 + lr;
            bfr[n] = *reinterpret_cast<const bf16x8*>(
                (const char*)&Bl[buf][0][0] + r * 64 + ((grp ^ (r & 3)) << 4));
        }
        #pragma unroll
        for (int m = 0; m < MF; ++m)
            #pragma unroll
            for (int n = 0; n < NF; ++n)
                acc[m][n] = __builtin_amdgcn_mfma_f32_16x16x32_bf16(af[m], bfr[n], acc[m][n], 0, 0, 0);
        __syncthreads();
        buf ^= 1;
    }

    #pragma unroll
    for (int m = 0; m < MF; ++m) {
        #pragma unroll
        for (int q = 0; q < 4; ++q) {
            int rowg = rowBase + wm * WM + m * 16 + grp * 4 + q;
            if (rowg >= M) continue;
            #pragma unroll
            for (int n = 0; n < NF; ++n) {
                int colg = colBase + wn * WN + n * 16 + lr;
                float v = acc[m][n][q] + bias[colg];
                if (RELU) v = fmaxf(v, 0.f);
                if (OBF16) Cb[(size_t)rowg * Nfull + colg] = f2bf(v);
                else       Cf[(size_t)rowg * Nfull + colg] = v;
                if (WQ8)   Cq[(size_t)rowg * Nfull + colg] = f2fp8(v);
            }
        }
    }
}

extern "C" void kernel_launch(void* const* d_in, const int* in_sizes, int n_in,
                              void* d_out, int out_size, void* d_ws, size_t ws_size,
                              hipStream_t stream) {
    const float* x  = (const float*)d_in[0];
    const float* W1 = (const float*)d_in[1];
    const float* b1 = (const float*)d_in[2];
    const float* W2 = (const float*)d_in[3];
    const float* b2 = (const float*)d_in[4];
    const int* src1 = (const int*)d_in[5];
    const int* dst1 = (const int*)d_in[6];
    const int* src2 = (const int*)d_in[7];
    const int* dst2 = (const int*)d_in[8];
    const int E1 = in_sizes[5];
    const int E2 = in_sizes[7];
    const int N_SRC1 = in_sizes[0] / FEAT;   // 200000
    float* out = (float*)d_out;

    char* ws = (char*)d_ws;
    size_t o = 0;
    auto carve = [&](size_t bytes) { char* p = ws + o; o = (o + bytes + 255) & ~(size_t)255; return p; };
    int*    degs = (int*)   carve((size_t)(N_DST1 + N_DST2) * 4);
    int*    deg1 = degs;
    int*    deg2 = degs + N_DST1;
    int*    off1 = (int*)   carve((size_t)(N_DST1 + 1) * 4);
    int*    pos1 = (int*)   carve((size_t)N_DST1 * 4);
    int*    csr1 = (int*)   carve((size_t)E1 * 4);
    ushort* hN1b = (ushort*)carve((size_t)N_DST1 * FEAT * 2);
    ushort* hb   = (ushort*)carve((size_t)N_DST1 * FEAT * 2);
    u8*     hq   = (u8*)    carve((size_t)N_DST1 * FEAT);
    int*    off2 = (int*)   carve((size_t)(N_DST2 + 1) * 4);
    int*    pos2 = (int*)   carve((size_t)N_DST2 * 4);
    int*    csr2 = (int*)   carve((size_t)E2 * 4);
    ushort* hN2b = (ushort*)carve((size_t)N_DST2 * FEAT * 2);
    ushort* W1T  = (ushort*)carve((size_t)256 * 512 * 2);
    ushort* W2T  = (ushort*)carve((size_t)64 * 512 * 2);
    ushort* xb = (ushort*)carve((size_t)N_DST1 * FEAT * 2);
    size_t q_bytes = (size_t)N_SRC1 * FEAT;           // 1B per element
    bool fp8path = (o + q_bytes) <= ws_size;
    u32* xq = fp8path ? (u32*)carve(q_bytes) : nullptr;

    // ---- fused prep: x->fp8(all)+bf16(head) + degree count + W transposes ----
    (void)hipMemsetAsync(degs, 0, (size_t)(N_DST1 + N_DST2) * 4, stream);
    {
        int n8  = (fp8path ? N_SRC1 : N_DST1) * FEAT / 8;
        int n8h = N_DST1 * FEAT / 8;
        int tot = n8 + (E1 >> 2) + (E2 >> 2) + (E1 & 3) + (E2 & 3) + 512 * 256 + 512 * 64;
        prep_kernel<<<(tot + 255) / 256, 256, 0, stream>>>(
            x, xb, xq, n8, n8h, dst1, E1, deg1, dst2, E2, deg2, W1, W1T, W2, W2T);
    }
    // ---- dual scan (2 blocks) ----
    scan_kernel<<<2, 1024, 0, stream>>>(deg1, N_DST1, off1, pos1, deg2, N_DST2, off2, pos2);
    // ---- scatter (both graphs), 4 edges/thread ----
    {
        int tot = (E1 >> 2) + (E2 >> 2) + (E1 & 3) + (E2 & 3);
        scatter_csr2_kernel<<<(tot + 255) / 256, 256, 0, stream>>>(
            src1, dst1, E1, pos1, csr1, src2, dst2, E2, pos2, csr2);
    }

    if (fp8path) {
        // ---- layer 1: fp8 aggregate (wave-per-dst) + GEMM (writes bf16 h + fp8 h) ----
        seg_mean_fp8_kernel<<<(N_DST1 + 7) / 8, 512, 0, stream>>>(
            xq, off1, csr1, hN1b, N_DST1);
        gemm_mfma_kernel<128, 256, 2, 4, true, true, true><<<dim3(1, (N_DST1 + 127) / 128), 512, 0, stream>>>(
            xb, hN1b, W1T, b1, hb, nullptr, hq, N_DST1, 256);

        // ---- layer 2: fp8 aggregate (L2/L3-resident) + GEMM (f32 out) ----
        seg_mean_fp8_kernel<<<(N_DST2 + 7) / 8, 512, 0, stream>>>(
            (const u32*)hq, off2, csr2, hN2b, N_DST2);
        gemm_mfma_kernel<64, 64, 2, 2, false, false, false><<<dim3(1, (N_DST2 + 63) / 64), 256, 0, stream>>>(
            hb, hN2b, W2T, b2, nullptr, out, nullptr, N_DST2, 64);
    } else {
        cvt_wt2_kernel<<<512, 320, 0, stream>>>(W1, W1T, W2, W2T);
        seg_mean_f32_kernel<<<N_DST1, 64, 0, stream>>>(x, off1, csr1, hN1b);
        gemm_mfma_kernel<128, 256, 2, 4, true, true, false><<<dim3(1, (N_DST1 + 127) / 128), 512, 0, stream>>>(
            xb, hN1b, W1T, b1, hb, nullptr, nullptr, N_DST1, 256);
        seg_mean_bf16_kernel<<<(N_DST2 + 7) / 8, 512, 0, stream>>>(hb, off2, csr2, hN2b, N_DST2);
        gemm_mfma_kernel<64, 64, 2, 2, false, false, false><<<dim3(1, (N_DST2 + 63) / 64), 256, 0, stream>>>(
            hb, hN2b, W2T, b2, nullptr, out, nullptr, N_DST2, 64);
    }
}